// Round 6
// baseline (389.689 us; speedup 1.0000x reference)
//
#include <hip/hip_runtime.h>
#include <hip/hip_bf16.h>

#define T_TOK 3136
#define DDIM  1024
#define HDIM  768
#define NEXP  23
#define TOPK  3
#define MTILE 128
#define NTILE 128
#define KTILE 32
#define LDSB  40            // B-tile LDS row stride (shorts): 80B rows, XOR-chunk swizzle
#define MAXTILES 128        // tile-map capacity: sum ntl <= 97 routed + 25 shared = 122
#define MAX_SLOTS 16384     // >= 12329 (routed, 128-padded) + 3200 (shared padded)
#define GATE_BLOCKS 1568    // 2 tokens per block, grid-stride
#define XCVT_BLOCKS 3136    // (T_TOK*DDIM/4)/256

typedef __attribute__((ext_vector_type(8))) short  short8;   // 8 bf16 = 16B (MFMA A/B frag / staging)
typedef __attribute__((ext_vector_type(4))) short  short4v;
typedef __attribute__((ext_vector_type(4))) float  floatx4;  // MFMA C/D frag

__device__ __forceinline__ short f2b(float f) {  // fp32 -> bf16, round-to-nearest-even
    union { float f; unsigned u; } v; v.f = f;
    unsigned r = v.u + 0x7FFFu + ((v.u >> 16) & 1u);
    return (short)(r >> 16);
}
__device__ __forceinline__ float b2f(short s) {
    union { unsigned u; float f; } v; v.u = ((unsigned)(unsigned short)s) << 16; return v.f;
}
__device__ __forceinline__ float gelu_exact(float v) {
    return 0.5f * v * (1.0f + erff(v * 0.70710678118654752f));
}
// direct global->LDS 16B async copy. LDS dest is wave-uniform base + lane*16 (m104/m97).
__device__ __forceinline__ void gld16(const short* g, short* l) {
    __builtin_amdgcn_global_load_lds(
        (const __attribute__((address_space(1))) void*)g,
        (__attribute__((address_space(3))) void*)l, 16, 0, 0);
}

// ---------------- prep: x -> bf16 (blocks 0..3135) + gate_w transpose (blocks 3136..3167) ----------------
__global__ __launch_bounds__(256) void prep_kernel(
    const float* __restrict__ x, short* __restrict__ xb,
    const float* __restrict__ gw, float* __restrict__ gwT)
{
    __shared__ float tile[32][33];
    if (blockIdx.x < XCVT_BLOCKS) {
        int i = blockIdx.x * 256 + threadIdx.x;           // float4 index
        float4 v = ((const float4*)x)[i];
        short4v s = { f2b(v.x), f2b(v.y), f2b(v.z), f2b(v.w) };
        ((short4v*)xb)[i] = s;
        return;
    }
    const int kt = blockIdx.x - XCVT_BLOCKS;              // 32 k-rows per block
    const int tx = threadIdx.x & 31, ty = threadIdx.x >> 5;
    #pragma unroll
    for (int i = 0; i < 4; i++) {
        int k = ty + i * 8;
        tile[k][tx] = (tx < NEXP) ? gw[(size_t)(kt * 32 + k) * NEXP + tx] : 0.f;
    }
    __syncthreads();
    #pragma unroll
    for (int i = 0; i < 4; i++) {
        int e = ty + i * 8;
        if (e < 24) gwT[(size_t)e * DDIM + kt * 32 + tx] = tile[tx][e];  // e=23 -> zeros (pad expert)
    }
}

// ---------------- gate: 2 tokens/block grid-stride; also accumulates Pf (fused preduce) ----------------
__global__ __launch_bounds__(256) void gate_kernel(
    const float* __restrict__ x, const float* __restrict__ gwT, const float* __restrict__ gb,
    float* __restrict__ Pf, int* __restrict__ top_idx, float* __restrict__ top_w)
{
    const int tid = threadIdx.x;
    const int lane = tid & 63, wave = tid >> 6;
    const int ebase = wave * 6;                      // waves cover experts 0..23 (23 = zero pad)
    __shared__ float sg[24];
    __shared__ float accP[NEXP];
    if (tid < NEXP) accP[tid] = 0.f;

    for (int t = blockIdx.x; t < T_TOK; t += GATE_BLOCKS) {
        const float4* xr4 = (const float4*)(x + (size_t)t * DDIM);
        float4 xv[4];
        #pragma unroll
        for (int j = 0; j < 4; j++) xv[j] = xr4[j * 64 + lane];

        // 6 independent fp64 chains; per j-step 6 independent float4 loads
        double a0 = 0, a1 = 0, a2 = 0, a3 = 0, a4 = 0, a5 = 0;
        #pragma unroll
        for (int j = 0; j < 4; j++) {
            const float4* gp = (const float4*)gwT + (size_t)ebase * 256 + j * 64 + lane;
            float4 g0 = gp[0 * 256], g1 = gp[1 * 256], g2 = gp[2 * 256];
            float4 g3 = gp[3 * 256], g4 = gp[4 * 256], g5 = gp[5 * 256];
            float4 xj = xv[j];
            a0 += (double)xj.x * g0.x + (double)xj.y * g0.y + (double)xj.z * g0.z + (double)xj.w * g0.w;
            a1 += (double)xj.x * g1.x + (double)xj.y * g1.y + (double)xj.z * g1.z + (double)xj.w * g1.w;
            a2 += (double)xj.x * g2.x + (double)xj.y * g2.y + (double)xj.z * g2.z + (double)xj.w * g2.w;
            a3 += (double)xj.x * g3.x + (double)xj.y * g3.y + (double)xj.z * g3.z + (double)xj.w * g3.w;
            a4 += (double)xj.x * g4.x + (double)xj.y * g4.y + (double)xj.z * g4.z + (double)xj.w * g4.w;
            a5 += (double)xj.x * g5.x + (double)xj.y * g5.y + (double)xj.z * g5.z + (double)xj.w * g5.w;
        }
        #pragma unroll
        for (int off = 32; off > 0; off >>= 1) {     // interleaved butterflies (6-wide ILP)
            a0 += __shfl_xor(a0, off);
            a1 += __shfl_xor(a1, off);
            a2 += __shfl_xor(a2, off);
            a3 += __shfl_xor(a3, off);
            a4 += __shfl_xor(a4, off);
            a5 += __shfl_xor(a5, off);
        }

        if (lane == 0) {
            double av[6] = { a0, a1, a2, a3, a4, a5 };
            #pragma unroll
            for (int i = 0; i < 6; i++) {
                int e = ebase + i;
                if (e < NEXP) {
                    float z = (float)av[i] + gb[e];
                    sg[e] = 1.0f / (1.0f + expf(-z));
                }
            }
        }
        __syncthreads();

        if (tid < NEXP) {
            float s = 0.f;
            #pragma unroll
            for (int e = 0; e < NEXP; e++) s += sg[e];
            accP[tid] += sg[tid] / s;                // fused preduce (same thread each iter)
        }
        if (tid == 0) {
            float v0 = -1.f, v1 = -1.f, v2 = -1.f; int i0 = 0, i1 = 0, i2 = 0;
            for (int e = 0; e < NEXP; e++) {
                float v = sg[e];
                if (v > v0)      { v2 = v1; i2 = i1; v1 = v0; i1 = i0; v0 = v; i0 = e; }
                else if (v > v1) { v2 = v1; i2 = i1; v1 = v; i1 = e; }
                else if (v > v2) { v2 = v; i2 = e; }
            }
            float ts = v0 + v1 + v2;
            top_idx[t * 3 + 0] = i0; top_w[t * 3 + 0] = v0 / ts;
            top_idx[t * 3 + 1] = i1; top_w[t * 3 + 1] = v1 / ts;
            top_idx[t * 3 + 2] = i2; top_w[t * 3 + 2] = v2 / ts;
        }
        __syncthreads();   // sg reused next token iteration
    }
    if (tid < NEXP) atomicAdd(&Pf[tid], accP[tid]);
}

// ---------------- route: hist + offsets + tile map + scatter + pad init + aux, ONE block ----------------
__global__ __launch_bounds__(1024) void route_kernel(
    const int* __restrict__ top_idx, const float* __restrict__ Pf,
    int* __restrict__ ntl,
    int* __restrict__ slot_t, int* __restrict__ slot_of,
    int* __restrict__ tmap_e, int* __restrict__ tmap_b,
    float* __restrict__ out_aux)
{
    __shared__ int h[NEXP];
    __shared__ int lfill[NEXP];
    __shared__ int soffs[NEXP + 1];
    __shared__ int sntl[NEXP + 1];
    const int tid = threadIdx.x;
    if (tid < NEXP) { h[tid] = 0; lfill[tid] = 0; }
    __syncthreads();
    for (int i = tid; i < T_TOK * 3; i += 1024) atomicAdd(&h[top_idx[i]], 1);
    __syncthreads();
    if (tid == 0) {
        int o = 0, ti = 0;
        for (int e = 0; e < NEXP; e++) {
            int c = h[e];
            int nt = (c + MTILE - 1) / MTILE;
            soffs[e] = o; sntl[e] = nt; ntl[e] = nt;
            for (int j = 0; j < nt; j++) { tmap_e[ti] = e; tmap_b[ti] = o + j * MTILE; ti++; }
            o += nt * MTILE;
        }
        int nts = (T_TOK + MTILE - 1) / MTILE;       // shared expert: all tokens
        soffs[NEXP] = o; sntl[NEXP] = nts; ntl[NEXP] = nts;
        for (int j = 0; j < nts; j++) { tmap_e[ti] = NEXP; tmap_b[ti] = o + j * MTILE; ti++; }
        ntl[NEXP + 1] = ti;                          // total tile count for the GEMM grids
        // aux loss (Pf final: gate completed before this kernel)
        float aux = 0.f;
        for (int e = 0; e < NEXP; e++) {
            float P = Pf[e] / (float)T_TOK;
            float F = (float)NEXP * (float)h[e] / (float)(TOPK * T_TOK);
            aux += P * F;
        }
        out_aux[0] = aux;
    }
    __syncthreads();
    // pad slots -> token 0 (only the padded tails; <= ~3K writes)
    for (int e = 0; e <= NEXP; e++) {
        int cnt = (e < NEXP) ? h[e] : T_TOK;
        int s0 = soffs[e] + cnt, s1 = soffs[e] + sntl[e] * MTILE;
        for (int s = s0 + tid; s < s1; s += 1024) slot_t[s] = 0;
    }
    // scatter (LDS fill counters, order-free within expert)
    for (int t = tid; t < T_TOK; t += 1024) {
        #pragma unroll
        for (int k = 0; k < TOPK; k++) {
            int e = top_idx[t * 3 + k];
            int pos = atomicAdd(&lfill[e], 1);
            int s = soffs[e] + pos;
            slot_t[s] = t;
            slot_of[t * 4 + k] = s;
        }
        int s = soffs[NEXP] + t;                     // shared expert bucket (no atomic)
        slot_t[s] = t;
        slot_of[t * 4 + 3] = s;
    }
}

// ---------------- GEMM1: hh[slot][h] = gelu(xb[tok] @ W1 + b1), bf16 out ----------------
// Pipelined 2-phase KSTEP=32 (proven round-3 structure) + XCD-locality block swizzle:
// xcd = L%8 owns 16 consecutive tiles x all 6 n-blocks -> A-tiles + W-panels stay in that L2.
__global__ __launch_bounds__(256) void gemm1_kernel(
    const short* __restrict__ xb,
    const float* __restrict__ w1, const float* __restrict__ b1,
    const float* __restrict__ ws1, const float* __restrict__ bs1,
    const int* __restrict__ tmap_e, const int* __restrict__ tmap_b,
    const int* __restrict__ ntl,
    const int* __restrict__ slot_t, short* __restrict__ hh)
{
    const int L = blockIdx.x;                         // 768 = 8 xcd x 16 y x 6 x
    const int xcd = L & 7, sl = L >> 3;
    const int ty = xcd * 16 + sl / 6, tx = sl % 6;
    if (ty >= ntl[NEXP + 1]) return;
    const int e = tmap_e[ty];
    const int slot_base = tmap_b[ty];
    const int n0 = tx * NTILE;
    const float* __restrict__ Wf = (e < NEXP) ? (w1 + (size_t)e * DDIM * HDIM) : ws1;  // [DDIM][HDIM] fp32
    const float* __restrict__ Bv = (e < NEXP) ? (b1 + (size_t)e * HDIM) : bs1;

    __shared__ __align__(16) short As[2][MTILE * KTILE];   // 2 x 8 KB
    __shared__ __align__(16) short Bs[2][NTILE * LDSB];    // 2 x 10 KB, swizzled chunks
    __shared__ int toks[MTILE];

    const int tid = threadIdx.x;
    for (int i = tid; i < MTILE; i += 256) toks[i] = slot_t[slot_base + i];

    const int lane = tid & 63, wave = tid >> 6;
    const int mbase = (wave & 1) * 64, nbase = (wave >> 1) * 64;
    const int lc = lane & 15, q = lane >> 4;
    const int xq8 = (q ^ ((lc >> 1) & 3)) << 3;       // B frag chunk (inverse swizzle), shorts

    // A staging: wave w covers rows {i*64 + w*16 + lane/4}, chunk (lane&3)*16B; LDS dest linear
    const int srow = wave * 16 + (lane >> 2);
    const int c8   = (lane & 3) * 8;

    __syncthreads();                                  // toks ready
    const short* gA0 = xb + (size_t)toks[srow]      * DDIM + c8;
    const short* gA1 = xb + (size_t)toks[64 + srow] * DDIM + c8;
    const int lofs0 = wave * 512, lofs1 = 2048 + wave * 512;

    // B staging: wave = k-octet g (0..3), lane = n-pair cn (0..63)
    const int g = wave, cn = lane;
    const float* gW = Wf + (size_t)(8 * g) * HDIM + n0 + 2 * cn;
    const int bws = (g ^ (cn & 3)) << 3;              // write chunk pos, shorts
    const int bofs0 = (2 * cn) * LDSB + bws, bofs1 = (2 * cn + 1) * LDSB + bws;

    floatx4 acc[4][4];
    #pragma unroll
    for (int m = 0; m < 4; m++)
        #pragma unroll
        for (int n = 0; n < 4; n++) acc[m][n] = (floatx4)0.f;

    const int NT = DDIM / KTILE;                      // 32
    float2 f[8];
    // prologue: stage t=0 into buf0, preload B regs for t=1
    #pragma unroll
    for (int j = 0; j < 8; j++) f[j] = *(const float2*)(gW + (size_t)j * HDIM);
    gld16(gA0, &As[0][lofs0]);
    gld16(gA1, &As[0][lofs1]);
    {
        short8 s0, s1;
        #pragma unroll
        for (int j = 0; j < 8; j++) { s0[j] = f2b(f[j].x); s1[j] = f2b(f[j].y); }
        *(short8*)&Bs[0][bofs0] = s0;
        *(short8*)&Bs[0][bofs1] = s1;
    }
    #pragma unroll
    for (int j = 0; j < 8; j++) f[j] = *(const float2*)(gW + (size_t)(KTILE + j) * HDIM);
    __syncthreads();                                  // t=0 ready; f holds t=1

    for (int t = 0; t < NT; t++) {
        const int cur = t & 1;
        if (t + 1 < NT) {                             // stage t+1 into other buffer (async)
            gld16(gA0 + (t + 1) * KTILE, &As[cur ^ 1][lofs0]);
            gld16(gA1 + (t + 1) * KTILE, &As[cur ^ 1][lofs1]);
            short8 s0, s1;
            #pragma unroll
            for (int j = 0; j < 8; j++) { s0[j] = f2b(f[j].x); s1[j] = f2b(f[j].y); }
            *(short8*)&Bs[cur ^ 1][bofs0] = s0;
            *(short8*)&Bs[cur ^ 1][bofs1] = s1;
        }
        if (t + 2 < NT) {                             // refill B regs for t+2 (overlaps MFMA)
            #pragma unroll
            for (int j = 0; j < 8; j++)
                f[j] = *(const float2*)(gW + (size_t)((t + 2) * KTILE + j) * HDIM);
        }
        short8 af[4], bf[4];
        #pragma unroll
        for (int m = 0; m < 4; m++) af[m] = *(const short8*)&As[cur][(mbase + m * 16 + lc) * KTILE + q * 8];
        #pragma unroll
        for (int n = 0; n < 4; n++) bf[n] = *(const short8*)&Bs[cur][(nbase + n * 16 + lc) * LDSB + xq8];
        #pragma unroll
        for (int m = 0; m < 4; m++)
            #pragma unroll
            for (int n = 0; n < 4; n++)
                acc[m][n] = __builtin_amdgcn_mfma_f32_16x16x32_bf16(af[m], bf[n], acc[m][n], 0, 0, 0);
        __syncthreads();                              // drains staging; t+1 buffers ready
    }

    #pragma unroll
    for (int n = 0; n < 4; n++) {
        const int col = n0 + nbase + n * 16 + lc;
        const float bb = Bv[col];
        #pragma unroll
        for (int m = 0; m < 4; m++) {
            const int rbase = slot_base + mbase + m * 16 + q * 4;
            #pragma unroll
            for (int r = 0; r < 4; r++) {
                float v = acc[m][n][r] + bb;
                hh[(size_t)(rbase + r) * HDIM + col] = f2b(gelu_exact(v));
            }
        }
    }
}

// ---------------- GEMM2: eo[slot][d] = hh[slot] @ W2 + b2 (bf16, unweighted), same pipeline ----------------
__global__ __launch_bounds__(256) void gemm2_kernel(
    const short* __restrict__ hh,
    const float* __restrict__ w2, const float* __restrict__ b2,
    const float* __restrict__ ws2, const float* __restrict__ bs2,
    const int* __restrict__ tmap_e, const int* __restrict__ tmap_b,
    const int* __restrict__ ntl,
    short* __restrict__ eo)
{
    const int L = blockIdx.x;                         // 1024 = 8 xcd x 16 y x 8 x
    const int xcd = L & 7, sl = L >> 3;
    const int ty = xcd * 16 + sl / 8, tx = sl & 7;
    if (ty >= ntl[NEXP + 1]) return;
    const int e = tmap_e[ty];
    const int slot_base = tmap_b[ty];
    const int n0 = tx * NTILE;
    const float* __restrict__ Wf = (e < NEXP) ? (w2 + (size_t)e * HDIM * DDIM) : ws2;  // [HDIM][DDIM] fp32
    const float* __restrict__ Bv = (e < NEXP) ? (b2 + (size_t)e * DDIM) : bs2;

    __shared__ __align__(16) short As[2][MTILE * KTILE];
    __shared__ __align__(16) short Bs[2][NTILE * LDSB];

    const int tid = threadIdx.x;
    const int lane = tid & 63, wave = tid >> 6;
    const int mbase = (wave & 1) * 64, nbase = (wave >> 1) * 64;
    const int lc = lane & 15, q = lane >> 4;
    const int xq8 = (q ^ ((lc >> 1) & 3)) << 3;

    const int srow = wave * 16 + (lane >> 2);
    const int c8   = (lane & 3) * 8;

    const short* gA0 = hh + (size_t)(slot_base + srow)      * HDIM + c8;   // slot rows contiguous
    const short* gA1 = hh + (size_t)(slot_base + 64 + srow) * HDIM + c8;
    const int lofs0 = wave * 512, lofs1 = 2048 + wave * 512;

    const int g = wave, cn = lane;
    const float* gW = Wf + (size_t)(8 * g) * DDIM + n0 + 2 * cn;
    const int bws = (g ^ (cn & 3)) << 3;
    const int bofs0 = (2 * cn) * LDSB + bws, bofs1 = (2 * cn + 1) * LDSB + bws;

    floatx4 acc[4][4];
    #pragma unroll
    for (int m = 0; m < 4; m++)
        #pragma unroll
        for (int n = 0; n < 4; n++) acc[m][n] = (floatx4)0.f;

    const int NT = HDIM / KTILE;                      // 24
    float2 f[8];
    #pragma unroll
    for (int j = 0; j < 8; j++) f[j] = *(const float2*)(gW + (size_t)j * DDIM);
    gld16(gA0, &As[0][lofs0]);
    gld16(gA1, &As[0][lofs1]);
    {
        short8 s0, s1;
        #pragma unroll
        for (int j = 0; j < 8; j++) { s0[j] = f2b(f[j].x); s1[j] = f2b(f[j].y); }
        *(short8*)&Bs[0][bofs0] = s0;
        *(short8*)&Bs[0][bofs1] = s1;
    }
    #pragma unroll
    for (int j = 0; j < 8; j++) f[j] = *(const float2*)(gW + (size_t)(KTILE + j) * DDIM);
    __syncthreads();

    for (int t = 0; t < NT; t++) {
        const int cur = t & 1;
        if (t + 1 < NT) {
            gld16(gA0 + (t + 1) * KTILE, &As[cur ^ 1][lofs0]);
            gld16(gA1 + (t + 1) * KTILE, &As[cur ^ 1][lofs1]);
            short8 s0, s1;
            #pragma unroll
            for (int j = 0; j < 8; j++) { s0[j] = f2b(f[j].x); s1[j] = f2b(f[j].y); }
            *(short8*)&Bs[cur ^ 1][bofs0] = s0;
            *(short8*)&Bs[cur ^ 1][bofs1] = s1;
        }
        if (t + 2 < NT) {
            #pragma unroll
            for (int j = 0; j < 8; j++)
                f[j] = *(const float2*)(gW + (size_t)((t + 2) * KTILE + j) * DDIM);
        }
        short8 af[4], bf[4];
        #pragma unroll
        for (int m = 0; m < 4; m++) af[m] = *(const short8*)&As[cur][(mbase + m * 16 + lc) * KTILE + q * 8];
        #pragma unroll
        for (int n = 0; n < 4; n++) bf[n] = *(const short8*)&Bs[cur][(nbase + n * 16 + lc) * LDSB + xq8];
        #pragma unroll
        for (int m = 0; m < 4; m++)
            #pragma unroll
            for (int n = 0; n < 4; n++)
                acc[m][n] = __builtin_amdgcn_mfma_f32_16x16x32_bf16(af[m], bf[n], acc[m][n], 0, 0, 0);
        __syncthreads();
    }

    #pragma unroll
    for (int n = 0; n < 4; n++) {
        const int col = n0 + nbase + n * 16 + lc;
        const float bb = Bv[col];
        #pragma unroll
        for (int m = 0; m < 4; m++) {
            const int rbase = slot_base + mbase + m * 16 + q * 4;
            #pragma unroll
            for (int r = 0; r < 4; r++)
                eo[(size_t)(rbase + r) * DDIM + col] = f2b(acc[m][n][r] + bb);
        }
    }
}

// ---------------- combine: out[t] = eo[shared] + sum_k tw_k * eo[slot_k] ----------------
__global__ __launch_bounds__(256) void combine_kernel(
    const short* __restrict__ eo, const float* __restrict__ top_w,
    const int* __restrict__ slot_of, float* __restrict__ out)
{
    const int t = blockIdx.x;
    const int c = threadIdx.x * 4;
    const int s0 = slot_of[t * 4 + 0], s1 = slot_of[t * 4 + 1];
    const int s2 = slot_of[t * 4 + 2], s3 = slot_of[t * 4 + 3];
    const float w0 = top_w[t * 3 + 0], w1 = top_w[t * 3 + 1], w2 = top_w[t * 3 + 2];
    short4v a = *(const short4v*)(eo + (size_t)s0 * DDIM + c);
    short4v b = *(const short4v*)(eo + (size_t)s1 * DDIM + c);
    short4v d = *(const short4v*)(eo + (size_t)s2 * DDIM + c);
    short4v s = *(const short4v*)(eo + (size_t)s3 * DDIM + c);
    float4 o;
    o.x = b2f(s.x) + w0 * b2f(a.x) + w1 * b2f(b.x) + w2 * b2f(d.x);
    o.y = b2f(s.y) + w0 * b2f(a.y) + w1 * b2f(b.y) + w2 * b2f(d.y);
    o.z = b2f(s.z) + w0 * b2f(a.z) + w1 * b2f(b.z) + w2 * b2f(d.z);
    o.w = b2f(s.w) + w0 * b2f(a.w) + w1 * b2f(b.w) + w2 * b2f(d.w);
    *(float4*)(out + (size_t)t * DDIM + c) = o;
}

extern "C" void kernel_launch(void* const* d_in, const int* in_sizes, int n_in,
                              void* d_out, int out_size, void* d_ws, size_t ws_size,
                              hipStream_t stream)
{
    const float* x   = (const float*)d_in[0];
    const float* gw  = (const float*)d_in[1];
    const float* gb  = (const float*)d_in[2];
    const float* w1  = (const float*)d_in[3];
    const float* b1  = (const float*)d_in[4];
    const float* w2  = (const float*)d_in[5];
    const float* b2  = (const float*)d_in[6];
    const float* ws1 = (const float*)d_in[7];
    const float* bs1 = (const float*)d_in[8];
    const float* ws2 = (const float*)d_in[9];
    const float* bs2 = (const float*)d_in[10];
    float* out = (float*)d_out;

    char* p = (char*)d_ws;
    auto alloc = [&](size_t bytes) -> char* {
        char* r = p; p += (bytes + 255) & ~(size_t)255; return r;
    };
    int*   top_idx  = (int*)  alloc((size_t)T_TOK * 3 * 4);
    float* top_w    = (float*)alloc((size_t)T_TOK * 3 * 4);
    float* Pf       = (float*)alloc(NEXP * 4);
    int*   ntl      = (int*)  alloc((NEXP + 2) * 4);
    int*   slot_t   = (int*)  alloc((size_t)MAX_SLOTS * 4);
    int*   slot_of  = (int*)  alloc((size_t)T_TOK * 4 * 4);
    int*   tmap_e   = (int*)  alloc((size_t)MAXTILES * 4);
    int*   tmap_b   = (int*)  alloc((size_t)MAXTILES * 4);
    float* gwT      = (float*)alloc((size_t)24 * DDIM * 4);    // 24 rows: expert 23 = zero pad
    short* xb       = (short*)alloc((size_t)T_TOK * DDIM * 2);
    short* hh       = (short*)alloc((size_t)MAX_SLOTS * HDIM * 2);
    short* eo       = (short*)alloc((size_t)MAX_SLOTS * DDIM * 2);

    hipMemsetAsync(Pf, 0, NEXP * 4, stream);

    prep_kernel<<<XCVT_BLOCKS + DDIM / 32, 256, 0, stream>>>(x, xb, gw, gwT);
    gate_kernel<<<GATE_BLOCKS, 256, 0, stream>>>(x, gwT, gb, Pf, top_idx, top_w);
    route_kernel<<<1, 1024, 0, stream>>>(top_idx, Pf, ntl, slot_t, slot_of,
                                         tmap_e, tmap_b, out + (size_t)T_TOK * DDIM);
    gemm1_kernel<<<8 * 16 * 6, 256, 0, stream>>>(
        xb, w1, b1, ws1, bs1, tmap_e, tmap_b, ntl, slot_t, hh);
    gemm2_kernel<<<8 * 16 * 8, 256, 0, stream>>>(
        hh, w2, b2, ws2, bs2, tmap_e, tmap_b, ntl, eo);
    combine_kernel<<<T_TOK, 256, 0, stream>>>(eo, top_w, slot_of, out);
}

// Round 7
// 380.010 us; speedup vs baseline: 1.0255x; 1.0255x over previous
//
#include <hip/hip_runtime.h>
#include <hip/hip_bf16.h>

#define T_TOK 3136
#define DDIM  1024
#define HDIM  768
#define NEXP  23
#define TOPK  3
#define MTILE 128
#define NTILE 128
#define KTILE 32
#define LDSB  40            // B-tile LDS row stride (shorts): 80B rows, XOR-chunk swizzle
#define MAXTILES 128        // tile-map capacity: sum ntl <= 97 routed + 25 shared = 122
#define MAX_SLOTS 16384     // >= 12329 (routed, 128-padded) + 3200 (shared padded)
#define GATE_BLOCKS 1568    // 2 tokens per block, grid-stride
#define XCVT_BLOCKS 3136    // (T_TOK*DDIM/4)/256

typedef __attribute__((ext_vector_type(8))) short  short8;   // 8 bf16 = 16B (MFMA A/B frag / staging)
typedef __attribute__((ext_vector_type(4))) short  short4v;
typedef __attribute__((ext_vector_type(4))) float  floatx4;  // MFMA C/D frag

__device__ __forceinline__ short f2b(float f) {  // fp32 -> bf16, round-to-nearest-even
    union { float f; unsigned u; } v; v.f = f;
    unsigned r = v.u + 0x7FFFu + ((v.u >> 16) & 1u);
    return (short)(r >> 16);
}
__device__ __forceinline__ float b2f(short s) {
    union { unsigned u; float f; } v; v.u = ((unsigned)(unsigned short)s) << 16; return v.f;
}
__device__ __forceinline__ float gelu_exact(float v) {
    return 0.5f * v * (1.0f + erff(v * 0.70710678118654752f));
}
// direct global->LDS 16B async copy. LDS dest is wave-uniform base + lane*16 (m104/m97).
__device__ __forceinline__ void gld16(const short* g, short* l) {
    __builtin_amdgcn_global_load_lds(
        (const __attribute__((address_space(1))) void*)g,
        (__attribute__((address_space(3))) void*)l, 16, 0, 0);
}
// counted-vmcnt barrier (T4): leave the 8 in-flight B reg-loads outstanding across the barrier;
// the 4 older gld16 (A-tile) are forced complete. lgkmcnt(0) covers the B ds_writes.
__device__ __forceinline__ void bar_cnt8() {
    asm volatile("s_waitcnt vmcnt(8) lgkmcnt(0)" ::: "memory");
    __builtin_amdgcn_s_barrier();
    __builtin_amdgcn_sched_barrier(0);
}
__device__ __forceinline__ void bar_cnt0() {      // tail iterations: no younger loads to count against
    asm volatile("s_waitcnt vmcnt(0) lgkmcnt(0)" ::: "memory");
    __builtin_amdgcn_s_barrier();
    __builtin_amdgcn_sched_barrier(0);
}

// ---------------- prep: x -> bf16 (blocks 0..3135) + gate_w transpose + Pf zero ----------------
__global__ __launch_bounds__(256) void prep_kernel(
    const float* __restrict__ x, short* __restrict__ xb,
    const float* __restrict__ gw, float* __restrict__ gwT, float* __restrict__ Pf)
{
    __shared__ float tile[32][33];
    if (blockIdx.x < XCVT_BLOCKS) {
        if (blockIdx.x == 0 && threadIdx.x < NEXP) Pf[threadIdx.x] = 0.f;  // replaces memset dispatch
        int i = blockIdx.x * 256 + threadIdx.x;           // float4 index
        float4 v = ((const float4*)x)[i];
        short4v s = { f2b(v.x), f2b(v.y), f2b(v.z), f2b(v.w) };
        ((short4v*)xb)[i] = s;
        return;
    }
    const int kt = blockIdx.x - XCVT_BLOCKS;              // 32 k-rows per block
    const int tx = threadIdx.x & 31, ty = threadIdx.x >> 5;
    #pragma unroll
    for (int i = 0; i < 4; i++) {
        int k = ty + i * 8;
        tile[k][tx] = (tx < NEXP) ? gw[(size_t)(kt * 32 + k) * NEXP + tx] : 0.f;
    }
    __syncthreads();
    #pragma unroll
    for (int i = 0; i < 4; i++) {
        int e = ty + i * 8;
        if (e < 24) gwT[(size_t)e * DDIM + kt * 32 + tx] = tile[tx][e];  // e=23 -> zeros (pad expert)
    }
}

// ---------------- gate: 2 tokens/block grid-stride; also accumulates Pf (fused preduce) ----------------
__global__ __launch_bounds__(256) void gate_kernel(
    const float* __restrict__ x, const float* __restrict__ gwT, const float* __restrict__ gb,
    float* __restrict__ Pf, int* __restrict__ top_idx, float* __restrict__ top_w)
{
    const int tid = threadIdx.x;
    const int lane = tid & 63, wave = tid >> 6;
    const int ebase = wave * 6;                      // waves cover experts 0..23 (23 = zero pad)
    __shared__ float sg[24];
    __shared__ float accP[NEXP];
    if (tid < NEXP) accP[tid] = 0.f;

    for (int t = blockIdx.x; t < T_TOK; t += GATE_BLOCKS) {
        const float4* xr4 = (const float4*)(x + (size_t)t * DDIM);
        float4 xv[4];
        #pragma unroll
        for (int j = 0; j < 4; j++) xv[j] = xr4[j * 64 + lane];

        // 6 independent fp64 chains; per j-step 6 independent float4 loads
        double a0 = 0, a1 = 0, a2 = 0, a3 = 0, a4 = 0, a5 = 0;
        #pragma unroll
        for (int j = 0; j < 4; j++) {
            const float4* gp = (const float4*)gwT + (size_t)ebase * 256 + j * 64 + lane;
            float4 g0 = gp[0 * 256], g1 = gp[1 * 256], g2 = gp[2 * 256];
            float4 g3 = gp[3 * 256], g4 = gp[4 * 256], g5 = gp[5 * 256];
            float4 xj = xv[j];
            a0 += (double)xj.x * g0.x + (double)xj.y * g0.y + (double)xj.z * g0.z + (double)xj.w * g0.w;
            a1 += (double)xj.x * g1.x + (double)xj.y * g1.y + (double)xj.z * g1.z + (double)xj.w * g1.w;
            a2 += (double)xj.x * g2.x + (double)xj.y * g2.y + (double)xj.z * g2.z + (double)xj.w * g2.w;
            a3 += (double)xj.x * g3.x + (double)xj.y * g3.y + (double)xj.z * g3.z + (double)xj.w * g3.w;
            a4 += (double)xj.x * g4.x + (double)xj.y * g4.y + (double)xj.z * g4.z + (double)xj.w * g4.w;
            a5 += (double)xj.x * g5.x + (double)xj.y * g5.y + (double)xj.z * g5.z + (double)xj.w * g5.w;
        }
        #pragma unroll
        for (int off = 32; off > 0; off >>= 1) {     // interleaved butterflies (6-wide ILP)
            a0 += __shfl_xor(a0, off);
            a1 += __shfl_xor(a1, off);
            a2 += __shfl_xor(a2, off);
            a3 += __shfl_xor(a3, off);
            a4 += __shfl_xor(a4, off);
            a5 += __shfl_xor(a5, off);
        }

        if (lane == 0) {
            double av[6] = { a0, a1, a2, a3, a4, a5 };
            #pragma unroll
            for (int i = 0; i < 6; i++) {
                int e = ebase + i;
                if (e < NEXP) {
                    float z = (float)av[i] + gb[e];
                    sg[e] = 1.0f / (1.0f + expf(-z));
                }
            }
        }
        __syncthreads();

        if (tid < NEXP) {
            float s = 0.f;
            #pragma unroll
            for (int e = 0; e < NEXP; e++) s += sg[e];
            accP[tid] += sg[tid] / s;                // fused preduce (same thread each iter)
        }
        if (tid == 0) {
            float v0 = -1.f, v1 = -1.f, v2 = -1.f; int i0 = 0, i1 = 0, i2 = 0;
            for (int e = 0; e < NEXP; e++) {
                float v = sg[e];
                if (v > v0)      { v2 = v1; i2 = i1; v1 = v0; i1 = i0; v0 = v; i0 = e; }
                else if (v > v1) { v2 = v1; i2 = i1; v1 = v; i1 = e; }
                else if (v > v2) { v2 = v; i2 = e; }
            }
            float ts = v0 + v1 + v2;
            top_idx[t * 3 + 0] = i0; top_w[t * 3 + 0] = v0 / ts;
            top_idx[t * 3 + 1] = i1; top_w[t * 3 + 1] = v1 / ts;
            top_idx[t * 3 + 2] = i2; top_w[t * 3 + 2] = v2 / ts;
        }
        __syncthreads();   // sg reused next token iteration
    }
    if (tid < NEXP) atomicAdd(&Pf[tid], accP[tid]);
}

// ---------------- route: hist + offsets + tile map + scatter + pad init + aux, ONE block ----------------
__global__ __launch_bounds__(1024) void route_kernel(
    const int* __restrict__ top_idx, const float* __restrict__ Pf,
    int* __restrict__ ntl,
    int* __restrict__ slot_t, int* __restrict__ slot_of,
    int* __restrict__ tmap_e, int* __restrict__ tmap_b,
    float* __restrict__ out_aux)
{
    __shared__ int h[NEXP];
    __shared__ int lfill[NEXP];
    __shared__ int soffs[NEXP + 1];
    __shared__ int sntl[NEXP + 1];
    const int tid = threadIdx.x;
    if (tid < NEXP) { h[tid] = 0; lfill[tid] = 0; }
    __syncthreads();
    for (int i = tid; i < T_TOK * 3; i += 1024) atomicAdd(&h[top_idx[i]], 1);
    __syncthreads();
    if (tid == 0) {
        int o = 0, ti = 0;
        for (int e = 0; e < NEXP; e++) {
            int c = h[e];
            int nt = (c + MTILE - 1) / MTILE;
            soffs[e] = o; sntl[e] = nt; ntl[e] = nt;
            for (int j = 0; j < nt; j++) { tmap_e[ti] = e; tmap_b[ti] = o + j * MTILE; ti++; }
            o += nt * MTILE;
        }
        int nts = (T_TOK + MTILE - 1) / MTILE;       // shared expert: all tokens
        soffs[NEXP] = o; sntl[NEXP] = nts; ntl[NEXP] = nts;
        for (int j = 0; j < nts; j++) { tmap_e[ti] = NEXP; tmap_b[ti] = o + j * MTILE; ti++; }
        ntl[NEXP + 1] = ti;                          // total tile count for the GEMM grids
        // aux loss (Pf final: gate completed before this kernel)
        float aux = 0.f;
        for (int e = 0; e < NEXP; e++) {
            float P = Pf[e] / (float)T_TOK;
            float F = (float)NEXP * (float)h[e] / (float)(TOPK * T_TOK);
            aux += P * F;
        }
        out_aux[0] = aux;
    }
    __syncthreads();
    // pad slots -> token 0 (only the padded tails; <= ~3K writes)
    for (int e = 0; e <= NEXP; e++) {
        int cnt = (e < NEXP) ? h[e] : T_TOK;
        int s0 = soffs[e] + cnt, s1 = soffs[e] + sntl[e] * MTILE;
        for (int s = s0 + tid; s < s1; s += 1024) slot_t[s] = 0;
    }
    // scatter (LDS fill counters, order-free within expert)
    for (int t = tid; t < T_TOK; t += 1024) {
        #pragma unroll
        for (int k = 0; k < TOPK; k++) {
            int e = top_idx[t * 3 + k];
            int pos = atomicAdd(&lfill[e], 1);
            int s = soffs[e] + pos;
            slot_t[s] = t;
            slot_of[t * 4 + k] = s;
        }
        int s = soffs[NEXP] + t;                     // shared expert bucket (no atomic)
        slot_t[s] = t;
        slot_of[t * 4 + 3] = s;
    }
}

// ---------------- GEMM1: hh[slot][h] = gelu(xb[tok] @ W1 + b1), bf16 out ----------------
// 2-phase pipeline + XCD swizzle + counted-vmcnt barriers: per K-step issue {4 gld16, B stage,
// 8 B floads}; barrier waits vmcnt(8) -> only the gld16 drain, floads stay in flight.
__global__ __launch_bounds__(256) void gemm1_kernel(
    const short* __restrict__ xb,
    const float* __restrict__ w1, const float* __restrict__ b1,
    const float* __restrict__ ws1, const float* __restrict__ bs1,
    const int* __restrict__ tmap_e, const int* __restrict__ tmap_b,
    const int* __restrict__ ntl,
    const int* __restrict__ slot_t, short* __restrict__ hh)
{
    const int L = blockIdx.x;                         // 768 = 8 xcd x 16 y x 6 x
    const int xcd = L & 7, sl = L >> 3;
    const int ty = xcd * 16 + sl / 6, tx = sl % 6;
    if (ty >= ntl[NEXP + 1]) return;
    const int e = tmap_e[ty];
    const int slot_base = tmap_b[ty];
    const int n0 = tx * NTILE;
    const float* __restrict__ Wf = (e < NEXP) ? (w1 + (size_t)e * DDIM * HDIM) : ws1;  // [DDIM][HDIM] fp32
    const float* __restrict__ Bv = (e < NEXP) ? (b1 + (size_t)e * HDIM) : bs1;

    __shared__ __align__(16) short As[2][MTILE * KTILE];   // 2 x 8 KB
    __shared__ __align__(16) short Bs[2][NTILE * LDSB];    // 2 x 10 KB, swizzled chunks
    __shared__ int toks[MTILE];

    const int tid = threadIdx.x;
    for (int i = tid; i < MTILE; i += 256) toks[i] = slot_t[slot_base + i];

    const int lane = tid & 63, wave = tid >> 6;
    const int mbase = (wave & 1) * 64, nbase = (wave >> 1) * 64;
    const int lc = lane & 15, q = lane >> 4;
    const int xq8 = (q ^ ((lc >> 1) & 3)) << 3;       // B frag chunk (inverse swizzle), shorts

    // A staging: wave w covers rows {i*64 + w*16 + lane/4}, chunk (lane&3)*16B; LDS dest linear
    const int srow = wave * 16 + (lane >> 2);
    const int c8   = (lane & 3) * 8;

    __syncthreads();                                  // toks ready
    const short* gA0 = xb + (size_t)toks[srow]      * DDIM + c8;
    const short* gA1 = xb + (size_t)toks[64 + srow] * DDIM + c8;
    const int lofs0 = wave * 512, lofs1 = 2048 + wave * 512;

    // B staging: wave = k-octet g (0..3), lane = n-pair cn (0..63)
    const int g = wave, cn = lane;
    const float* gW = Wf + (size_t)(8 * g) * HDIM + n0 + 2 * cn;
    const int bws = (g ^ (cn & 3)) << 3;              // write chunk pos, shorts
    const int bofs0 = (2 * cn) * LDSB + bws, bofs1 = (2 * cn + 1) * LDSB + bws;

    floatx4 acc[4][4];
    #pragma unroll
    for (int m = 0; m < 4; m++)
        #pragma unroll
        for (int n = 0; n < 4; n++) acc[m][n] = (floatx4)0.f;

    const int NT = DDIM / KTILE;                      // 32
    float2 f[8];
    // prologue: stage t=0 into buf0, preload B regs for t=1
    #pragma unroll
    for (int j = 0; j < 8; j++) f[j] = *(const float2*)(gW + (size_t)j * HDIM);
    gld16(gA0, &As[0][lofs0]);
    gld16(gA1, &As[0][lofs1]);
    __builtin_amdgcn_sched_barrier(0);                // pin: gld16 issued before the floads below
    {
        short8 s0, s1;
        #pragma unroll
        for (int j = 0; j < 8; j++) { s0[j] = f2b(f[j].x); s1[j] = f2b(f[j].y); }
        *(short8*)&Bs[0][bofs0] = s0;
        *(short8*)&Bs[0][bofs1] = s1;
    }
    #pragma unroll
    for (int j = 0; j < 8; j++) f[j] = *(const float2*)(gW + (size_t)(KTILE + j) * HDIM);
    bar_cnt8();                                       // t=0 ready (gld16 drained); f(t=1) in flight

    for (int t = 0; t < NT; t++) {
        const int cur = t & 1;
        if (t + 1 < NT) {                             // stage t+1 into other buffer (async)
            gld16(gA0 + (t + 1) * KTILE, &As[cur ^ 1][lofs0]);
            gld16(gA1 + (t + 1) * KTILE, &As[cur ^ 1][lofs1]);
            __builtin_amdgcn_sched_barrier(0);        // keep gld16 oldest in the vmem queue
            short8 s0, s1;
            #pragma unroll
            for (int j = 0; j < 8; j++) { s0[j] = f2b(f[j].x); s1[j] = f2b(f[j].y); }
            *(short8*)&Bs[cur ^ 1][bofs0] = s0;
            *(short8*)&Bs[cur ^ 1][bofs1] = s1;
        }
        if (t + 2 < NT) {                             // refill B regs for t+2 (overlaps MFMA)
            #pragma unroll
            for (int j = 0; j < 8; j++)
                f[j] = *(const float2*)(gW + (size_t)((t + 2) * KTILE + j) * HDIM);
        }
        short8 af[4], bf[4];
        #pragma unroll
        for (int m = 0; m < 4; m++) af[m] = *(const short8*)&As[cur][(mbase + m * 16 + lc) * KTILE + q * 8];
        #pragma unroll
        for (int n = 0; n < 4; n++) bf[n] = *(const short8*)&Bs[cur][(nbase + n * 16 + lc) * LDSB + xq8];
        #pragma unroll
        for (int m = 0; m < 4; m++)
            #pragma unroll
            for (int n = 0; n < 4; n++)
                acc[m][n] = __builtin_amdgcn_mfma_f32_16x16x32_bf16(af[m], bf[n], acc[m][n], 0, 0, 0);
        if (t + 1 < NT) {
            if (t + 2 < NT) bar_cnt8();               // floads for t+2 stay in flight
            else            bar_cnt0();               // no younger loads -> full drain
        }
    }

    #pragma unroll
    for (int n = 0; n < 4; n++) {
        const int col = n0 + nbase + n * 16 + lc;
        const float bb = Bv[col];
        #pragma unroll
        for (int m = 0; m < 4; m++) {
            const int rbase = slot_base + mbase + m * 16 + q * 4;
            #pragma unroll
            for (int r = 0; r < 4; r++) {
                float v = acc[m][n][r] + bb;
                hh[(size_t)(rbase + r) * HDIM + col] = f2b(gelu_exact(v));
            }
        }
    }
}

// ---------------- GEMM2: eo[slot][d] = hh[slot] @ W2 + b2 (bf16, unweighted), same pipeline ----------------
__global__ __launch_bounds__(256) void gemm2_kernel(
    const short* __restrict__ hh,
    const float* __restrict__ w2, const float* __restrict__ b2,
    const float* __restrict__ ws2, const float* __restrict__ bs2,
    const int* __restrict__ tmap_e, const int* __restrict__ tmap_b,
    const int* __restrict__ ntl,
    short* __restrict__ eo)
{
    const int L = blockIdx.x;                         // 1024 = 8 xcd x 16 y x 8 x
    const int xcd = L & 7, sl = L >> 3;
    const int ty = xcd * 16 + sl / 8, tx = sl & 7;
    if (ty >= ntl[NEXP + 1]) return;
    const int e = tmap_e[ty];
    const int slot_base = tmap_b[ty];
    const int n0 = tx * NTILE;
    const float* __restrict__ Wf = (e < NEXP) ? (w2 + (size_t)e * HDIM * DDIM) : ws2;  // [HDIM][DDIM] fp32
    const float* __restrict__ Bv = (e < NEXP) ? (b2 + (size_t)e * DDIM) : bs2;

    __shared__ __align__(16) short As[2][MTILE * KTILE];
    __shared__ __align__(16) short Bs[2][NTILE * LDSB];

    const int tid = threadIdx.x;
    const int lane = tid & 63, wave = tid >> 6;
    const int mbase = (wave & 1) * 64, nbase = (wave >> 1) * 64;
    const int lc = lane & 15, q = lane >> 4;
    const int xq8 = (q ^ ((lc >> 1) & 3)) << 3;

    const int srow = wave * 16 + (lane >> 2);
    const int c8   = (lane & 3) * 8;

    const short* gA0 = hh + (size_t)(slot_base + srow)      * HDIM + c8;   // slot rows contiguous
    const short* gA1 = hh + (size_t)(slot_base + 64 + srow) * HDIM + c8;
    const int lofs0 = wave * 512, lofs1 = 2048 + wave * 512;

    const int g = wave, cn = lane;
    const float* gW = Wf + (size_t)(8 * g) * DDIM + n0 + 2 * cn;
    const int bws = (g ^ (cn & 3)) << 3;
    const int bofs0 = (2 * cn) * LDSB + bws, bofs1 = (2 * cn + 1) * LDSB + bws;

    floatx4 acc[4][4];
    #pragma unroll
    for (int m = 0; m < 4; m++)
        #pragma unroll
        for (int n = 0; n < 4; n++) acc[m][n] = (floatx4)0.f;

    const int NT = HDIM / KTILE;                      // 24
    float2 f[8];
    #pragma unroll
    for (int j = 0; j < 8; j++) f[j] = *(const float2*)(gW + (size_t)j * DDIM);
    gld16(gA0, &As[0][lofs0]);
    gld16(gA1, &As[0][lofs1]);
    __builtin_amdgcn_sched_barrier(0);
    {
        short8 s0, s1;
        #pragma unroll
        for (int j = 0; j < 8; j++) { s0[j] = f2b(f[j].x); s1[j] = f2b(f[j].y); }
        *(short8*)&Bs[0][bofs0] = s0;
        *(short8*)&Bs[0][bofs1] = s1;
    }
    #pragma unroll
    for (int j = 0; j < 8; j++) f[j] = *(const float2*)(gW + (size_t)(KTILE + j) * DDIM);
    bar_cnt8();

    for (int t = 0; t < NT; t++) {
        const int cur = t & 1;
        if (t + 1 < NT) {
            gld16(gA0 + (t + 1) * KTILE, &As[cur ^ 1][lofs0]);
            gld16(gA1 + (t + 1) * KTILE, &As[cur ^ 1][lofs1]);
            __builtin_amdgcn_sched_barrier(0);
            short8 s0, s1;
            #pragma unroll
            for (int j = 0; j < 8; j++) { s0[j] = f2b(f[j].x); s1[j] = f2b(f[j].y); }
            *(short8*)&Bs[cur ^ 1][bofs0] = s0;
            *(short8*)&Bs[cur ^ 1][bofs1] = s1;
        }
        if (t + 2 < NT) {
            #pragma unroll
            for (int j = 0; j < 8; j++)
                f[j] = *(const float2*)(gW + (size_t)((t + 2) * KTILE + j) * DDIM);
        }
        short8 af[4], bf[4];
        #pragma unroll
        for (int m = 0; m < 4; m++) af[m] = *(const short8*)&As[cur][(mbase + m * 16 + lc) * KTILE + q * 8];
        #pragma unroll
        for (int n = 0; n < 4; n++) bf[n] = *(const short8*)&Bs[cur][(nbase + n * 16 + lc) * LDSB + xq8];
        #pragma unroll
        for (int m = 0; m < 4; m++)
            #pragma unroll
            for (int n = 0; n < 4; n++)
                acc[m][n] = __builtin_amdgcn_mfma_f32_16x16x32_bf16(af[m], bf[n], acc[m][n], 0, 0, 0);
        if (t + 1 < NT) {
            if (t + 2 < NT) bar_cnt8();
            else            bar_cnt0();
        }
    }

    #pragma unroll
    for (int n = 0; n < 4; n++) {
        const int col = n0 + nbase + n * 16 + lc;
        const float bb = Bv[col];
        #pragma unroll
        for (int m = 0; m < 4; m++) {
            const int rbase = slot_base + mbase + m * 16 + q * 4;
            #pragma unroll
            for (int r = 0; r < 4; r++)
                eo[(size_t)(rbase + r) * DDIM + col] = f2b(acc[m][n][r] + bb);
        }
    }
}

// ---------------- combine: out[t] = eo[shared] + sum_k tw_k * eo[slot_k] ----------------
__global__ __launch_bounds__(256) void combine_kernel(
    const short* __restrict__ eo, const float* __restrict__ top_w,
    const int* __restrict__ slot_of, float* __restrict__ out)
{
    const int t = blockIdx.x;
    const int c = threadIdx.x * 4;
    const int s0 = slot_of[t * 4 + 0], s1 = slot_of[t * 4 + 1];
    const int s2 = slot_of[t * 4 + 2], s3 = slot_of[t * 4 + 3];
    const float w0 = top_w[t * 3 + 0], w1 = top_w[t * 3 + 1], w2 = top_w[t * 3 + 2];
    short4v a = *(const short4v*)(eo + (size_t)s0 * DDIM + c);
    short4v b = *(const short4v*)(eo + (size_t)s1 * DDIM + c);
    short4v d = *(const short4v*)(eo + (size_t)s2 * DDIM + c);
    short4v s = *(const short4v*)(eo + (size_t)s3 * DDIM + c);
    float4 o;
    o.x = b2f(s.x) + w0 * b2f(a.x) + w1 * b2f(b.x) + w2 * b2f(d.x);
    o.y = b2f(s.y) + w0 * b2f(a.y) + w1 * b2f(b.y) + w2 * b2f(d.y);
    o.z = b2f(s.z) + w0 * b2f(a.z) + w1 * b2f(b.z) + w2 * b2f(d.z);
    o.w = b2f(s.w) + w0 * b2f(a.w) + w1 * b2f(b.w) + w2 * b2f(d.w);
    *(float4*)(out + (size_t)t * DDIM + c) = o;
}

extern "C" void kernel_launch(void* const* d_in, const int* in_sizes, int n_in,
                              void* d_out, int out_size, void* d_ws, size_t ws_size,
                              hipStream_t stream)
{
    const float* x   = (const float*)d_in[0];
    const float* gw  = (const float*)d_in[1];
    const float* gb  = (const float*)d_in[2];
    const float* w1  = (const float*)d_in[3];
    const float* b1  = (const float*)d_in[4];
    const float* w2  = (const float*)d_in[5];
    const float* b2  = (const float*)d_in[6];
    const float* ws1 = (const float*)d_in[7];
    const float* bs1 = (const float*)d_in[8];
    const float* ws2 = (const float*)d_in[9];
    const float* bs2 = (const float*)d_in[10];
    float* out = (float*)d_out;

    char* p = (char*)d_ws;
    auto alloc = [&](size_t bytes) -> char* {
        char* r = p; p += (bytes + 255) & ~(size_t)255; return r;
    };
    int*   top_idx  = (int*)  alloc((size_t)T_TOK * 3 * 4);
    float* top_w    = (float*)alloc((size_t)T_TOK * 3 * 4);
    float* Pf       = (float*)alloc(NEXP * 4);
    int*   ntl      = (int*)  alloc((NEXP + 2) * 4);
    int*   slot_t   = (int*)  alloc((size_t)MAX_SLOTS * 4);
    int*   slot_of  = (int*)  alloc((size_t)T_TOK * 4 * 4);
    int*   tmap_e   = (int*)  alloc((size_t)MAXTILES * 4);
    int*   tmap_b   = (int*)  alloc((size_t)MAXTILES * 4);
    float* gwT      = (float*)alloc((size_t)24 * DDIM * 4);    // 24 rows: expert 23 = zero pad
    short* xb       = (short*)alloc((size_t)T_TOK * DDIM * 2);
    short* hh       = (short*)alloc((size_t)MAX_SLOTS * HDIM * 2);
    short* eo       = (short*)alloc((size_t)MAX_SLOTS * DDIM * 2);

    prep_kernel<<<XCVT_BLOCKS + DDIM / 32, 256, 0, stream>>>(x, xb, gw, gwT, Pf);
    gate_kernel<<<GATE_BLOCKS, 256, 0, stream>>>(x, gwT, gb, Pf, top_idx, top_w);
    route_kernel<<<1, 1024, 0, stream>>>(top_idx, Pf, ntl, slot_t, slot_of,
                                         tmap_e, tmap_b, out + (size_t)T_TOK * DDIM);
    gemm1_kernel<<<8 * 16 * 6, 256, 0, stream>>>(
        xb, w1, b1, ws1, bs1, tmap_e, tmap_b, ntl, slot_t, hh);
    gemm2_kernel<<<8 * 16 * 8, 256, 0, stream>>>(
        hh, w2, b2, ws2, bs2, tmap_e, tmap_b, ntl, eo);
    combine_kernel<<<T_TOK, 256, 0, stream>>>(eo, top_w, slot_of, out);
}

// Round 8
// 376.546 us; speedup vs baseline: 1.0349x; 1.0092x over previous
//
#include <hip/hip_runtime.h>
#include <hip/hip_bf16.h>

#define T_TOK 3136
#define DDIM  1024
#define HDIM  768
#define NEXP  23
#define TOPK  3
#define MTILE 128
#define NTILE 128
#define KTILE 32
#define LDSB  40            // B-tile LDS row stride (shorts): 80B rows, XOR-chunk swizzle
#define MAXTILES 128        // tile-map capacity: sum ntl <= 97 routed + 25 shared = 122
#define MAX_SLOTS 16384     // >= 12329 (routed, 128-padded) + 3200 (shared padded)
#define GATE_BLOCKS 1568    // 2 tokens per block, grid-stride
#define XCVT_BLOCKS 3136    // (T_TOK*DDIM/4)/256

typedef __attribute__((ext_vector_type(8))) short  short8;   // 8 bf16 = 16B (MFMA A/B frag / staging)
typedef __attribute__((ext_vector_type(4))) short  short4v;
typedef __attribute__((ext_vector_type(4))) float  floatx4;  // MFMA C/D frag

__device__ __forceinline__ short f2b(float f) {  // fp32 -> bf16, round-to-nearest-even
    union { float f; unsigned u; } v; v.f = f;
    unsigned r = v.u + 0x7FFFu + ((v.u >> 16) & 1u);
    return (short)(r >> 16);
}
__device__ __forceinline__ float b2f(short s) {
    union { unsigned u; float f; } v; v.u = ((unsigned)(unsigned short)s) << 16; return v.f;
}
__device__ __forceinline__ float gelu_exact(float v) {
    return 0.5f * v * (1.0f + erff(v * 0.70710678118654752f));
}
// direct global->LDS 16B async copy. LDS dest is wave-uniform base + lane*16 (m104/m97).
__device__ __forceinline__ void gld16(const short* g, short* l) {
    __builtin_amdgcn_global_load_lds(
        (const __attribute__((address_space(1))) void*)g,
        (__attribute__((address_space(3))) void*)l, 16, 0, 0);
}
// counted-vmcnt barrier (T4): the 1 gld16 (A-tile, oldest) drains; the 4 in-flight B reg-loads
// stay outstanding across the barrier. lgkmcnt(0) covers the B ds_writes.
__device__ __forceinline__ void bar_cnt4() {
    asm volatile("s_waitcnt vmcnt(4) lgkmcnt(0)" ::: "memory");
    __builtin_amdgcn_s_barrier();
    __builtin_amdgcn_sched_barrier(0);
}
__device__ __forceinline__ void bar_cnt0() {      // tail iterations: no younger loads to keep
    asm volatile("s_waitcnt vmcnt(0) lgkmcnt(0)" ::: "memory");
    __builtin_amdgcn_s_barrier();
    __builtin_amdgcn_sched_barrier(0);
}

// ---------------- prep: x -> bf16 (blocks 0..3135) + gate_w transpose + Pf zero ----------------
__global__ __launch_bounds__(256) void prep_kernel(
    const float* __restrict__ x, short* __restrict__ xb,
    const float* __restrict__ gw, float* __restrict__ gwT, float* __restrict__ Pf)
{
    __shared__ float tile[32][33];
    if (blockIdx.x < XCVT_BLOCKS) {
        if (blockIdx.x == 0 && threadIdx.x < NEXP) Pf[threadIdx.x] = 0.f;  // replaces memset dispatch
        int i = blockIdx.x * 256 + threadIdx.x;           // float4 index
        float4 v = ((const float4*)x)[i];
        short4v s = { f2b(v.x), f2b(v.y), f2b(v.z), f2b(v.w) };
        ((short4v*)xb)[i] = s;
        return;
    }
    const int kt = blockIdx.x - XCVT_BLOCKS;              // 32 k-rows per block
    const int tx = threadIdx.x & 31, ty = threadIdx.x >> 5;
    #pragma unroll
    for (int i = 0; i < 4; i++) {
        int k = ty + i * 8;
        tile[k][tx] = (tx < NEXP) ? gw[(size_t)(kt * 32 + k) * NEXP + tx] : 0.f;
    }
    __syncthreads();
    #pragma unroll
    for (int i = 0; i < 4; i++) {
        int e = ty + i * 8;
        if (e < 24) gwT[(size_t)e * DDIM + kt * 32 + tx] = tile[tx][e];  // e=23 -> zeros (pad expert)
    }
}

// ---------------- gate: 2 tokens/block grid-stride; also accumulates Pf (fused preduce) ----------------
__global__ __launch_bounds__(256) void gate_kernel(
    const float* __restrict__ x, const float* __restrict__ gwT, const float* __restrict__ gb,
    float* __restrict__ Pf, int* __restrict__ top_idx, float* __restrict__ top_w)
{
    const int tid = threadIdx.x;
    const int lane = tid & 63, wave = tid >> 6;
    const int ebase = wave * 6;                      // waves cover experts 0..23 (23 = zero pad)
    __shared__ float sg[24];
    __shared__ float accP[NEXP];
    if (tid < NEXP) accP[tid] = 0.f;

    for (int t = blockIdx.x; t < T_TOK; t += GATE_BLOCKS) {
        const float4* xr4 = (const float4*)(x + (size_t)t * DDIM);
        float4 xv[4];
        #pragma unroll
        for (int j = 0; j < 4; j++) xv[j] = xr4[j * 64 + lane];

        // 6 independent fp64 chains; per j-step 6 independent float4 loads
        double a0 = 0, a1 = 0, a2 = 0, a3 = 0, a4 = 0, a5 = 0;
        #pragma unroll
        for (int j = 0; j < 4; j++) {
            const float4* gp = (const float4*)gwT + (size_t)ebase * 256 + j * 64 + lane;
            float4 g0 = gp[0 * 256], g1 = gp[1 * 256], g2 = gp[2 * 256];
            float4 g3 = gp[3 * 256], g4 = gp[4 * 256], g5 = gp[5 * 256];
            float4 xj = xv[j];
            a0 += (double)xj.x * g0.x + (double)xj.y * g0.y + (double)xj.z * g0.z + (double)xj.w * g0.w;
            a1 += (double)xj.x * g1.x + (double)xj.y * g1.y + (double)xj.z * g1.z + (double)xj.w * g1.w;
            a2 += (double)xj.x * g2.x + (double)xj.y * g2.y + (double)xj.z * g2.z + (double)xj.w * g2.w;
            a3 += (double)xj.x * g3.x + (double)xj.y * g3.y + (double)xj.z * g3.z + (double)xj.w * g3.w;
            a4 += (double)xj.x * g4.x + (double)xj.y * g4.y + (double)xj.z * g4.z + (double)xj.w * g4.w;
            a5 += (double)xj.x * g5.x + (double)xj.y * g5.y + (double)xj.z * g5.z + (double)xj.w * g5.w;
        }
        #pragma unroll
        for (int off = 32; off > 0; off >>= 1) {     // interleaved butterflies (6-wide ILP)
            a0 += __shfl_xor(a0, off);
            a1 += __shfl_xor(a1, off);
            a2 += __shfl_xor(a2, off);
            a3 += __shfl_xor(a3, off);
            a4 += __shfl_xor(a4, off);
            a5 += __shfl_xor(a5, off);
        }

        if (lane == 0) {
            double av[6] = { a0, a1, a2, a3, a4, a5 };
            #pragma unroll
            for (int i = 0; i < 6; i++) {
                int e = ebase + i;
                if (e < NEXP) {
                    float z = (float)av[i] + gb[e];
                    sg[e] = 1.0f / (1.0f + expf(-z));
                }
            }
        }
        __syncthreads();

        if (tid < NEXP) {
            float s = 0.f;
            #pragma unroll
            for (int e = 0; e < NEXP; e++) s += sg[e];
            accP[tid] += sg[tid] / s;                // fused preduce (same thread each iter)
        }
        if (tid == 0) {
            float v0 = -1.f, v1 = -1.f, v2 = -1.f; int i0 = 0, i1 = 0, i2 = 0;
            for (int e = 0; e < NEXP; e++) {
                float v = sg[e];
                if (v > v0)      { v2 = v1; i2 = i1; v1 = v0; i1 = i0; v0 = v; i0 = e; }
                else if (v > v1) { v2 = v1; i2 = i1; v1 = v; i1 = e; }
                else if (v > v2) { v2 = v; i2 = e; }
            }
            float ts = v0 + v1 + v2;
            top_idx[t * 3 + 0] = i0; top_w[t * 3 + 0] = v0 / ts;
            top_idx[t * 3 + 1] = i1; top_w[t * 3 + 1] = v1 / ts;
            top_idx[t * 3 + 2] = i2; top_w[t * 3 + 2] = v2 / ts;
        }
        __syncthreads();   // sg reused next token iteration
    }
    if (tid < NEXP) atomicAdd(&Pf[tid], accP[tid]);
}

// ---------------- route: hist + offsets + tile map + scatter + pad init + aux, ONE block ----------------
__global__ __launch_bounds__(1024) void route_kernel(
    const int* __restrict__ top_idx, const float* __restrict__ Pf,
    int* __restrict__ ntl,
    int* __restrict__ slot_t, int* __restrict__ slot_of,
    int* __restrict__ tmap_e, int* __restrict__ tmap_b,
    float* __restrict__ out_aux)
{
    __shared__ int h[NEXP];
    __shared__ int lfill[NEXP];
    __shared__ int soffs[NEXP + 1];
    __shared__ int sntl[NEXP + 1];
    const int tid = threadIdx.x;
    if (tid < NEXP) { h[tid] = 0; lfill[tid] = 0; }
    __syncthreads();
    for (int i = tid; i < T_TOK * 3; i += 1024) atomicAdd(&h[top_idx[i]], 1);
    __syncthreads();
    if (tid == 0) {
        int o = 0, ti = 0;
        for (int e = 0; e < NEXP; e++) {
            int c = h[e];
            int nt = (c + MTILE - 1) / MTILE;
            soffs[e] = o; sntl[e] = nt; ntl[e] = nt;
            for (int j = 0; j < nt; j++) { tmap_e[ti] = e; tmap_b[ti] = o + j * MTILE; ti++; }
            o += nt * MTILE;
        }
        int nts = (T_TOK + MTILE - 1) / MTILE;       // shared expert: all tokens
        soffs[NEXP] = o; sntl[NEXP] = nts; ntl[NEXP] = nts;
        for (int j = 0; j < nts; j++) { tmap_e[ti] = NEXP; tmap_b[ti] = o + j * MTILE; ti++; }
        ntl[NEXP + 1] = ti;                          // total tile count for the GEMM grids
        // aux loss (Pf final: gate completed before this kernel)
        float aux = 0.f;
        for (int e = 0; e < NEXP; e++) {
            float P = Pf[e] / (float)T_TOK;
            float F = (float)NEXP * (float)h[e] / (float)(TOPK * T_TOK);
            aux += P * F;
        }
        out_aux[0] = aux;
    }
    __syncthreads();
    // pad slots -> token 0 (only the padded tails; <= ~3K writes)
    for (int e = 0; e <= NEXP; e++) {
        int cnt = (e < NEXP) ? h[e] : T_TOK;
        int s0 = soffs[e] + cnt, s1 = soffs[e] + sntl[e] * MTILE;
        for (int s = s0 + tid; s < s1; s += 1024) slot_t[s] = 0;
    }
    // scatter (LDS fill counters, order-free within expert)
    for (int t = tid; t < T_TOK; t += 1024) {
        #pragma unroll
        for (int k = 0; k < TOPK; k++) {
            int e = top_idx[t * 3 + k];
            int pos = atomicAdd(&lfill[e], 1);
            int s = soffs[e] + pos;
            slot_t[s] = t;
            slot_of[t * 4 + k] = s;
        }
        int s = soffs[NEXP] + t;                     // shared expert bucket (no atomic)
        slot_t[s] = t;
        slot_of[t * 4 + 3] = s;
    }
}

// ---------------- GEMM1: hh[slot][h] = gelu(xb[tok] @ W1 + b1), bf16 out ----------------
// 8-wave blocks (512 thr): wave grid 2M x 4N, wave owns 64x32 (acc[4][2], 8 MFMA/step).
// 2-phase pipeline + XCD swizzle + counted-vmcnt barrier (vmcnt(4): 1 gld16 drains, 4 B floads fly).
__global__ __launch_bounds__(512) void gemm1_kernel(
    const short* __restrict__ xb,
    const float* __restrict__ w1, const float* __restrict__ b1,
    const float* __restrict__ ws1, const float* __restrict__ bs1,
    const int* __restrict__ tmap_e, const int* __restrict__ tmap_b,
    const int* __restrict__ ntl,
    const int* __restrict__ slot_t, short* __restrict__ hh)
{
    const int L = blockIdx.x;                         // 768 = 8 xcd x 16 y x 6 x
    const int xcd = L & 7, sl = L >> 3;
    const int ty = xcd * 16 + sl / 6, tx = sl % 6;
    if (ty >= ntl[NEXP + 1]) return;
    const int e = tmap_e[ty];
    const int slot_base = tmap_b[ty];
    const int n0 = tx * NTILE;
    const float* __restrict__ Wf = (e < NEXP) ? (w1 + (size_t)e * DDIM * HDIM) : ws1;  // [DDIM][HDIM] fp32
    const float* __restrict__ Bv = (e < NEXP) ? (b1 + (size_t)e * HDIM) : bs1;

    __shared__ __align__(16) short As[2][MTILE * KTILE];   // 2 x 8 KB
    __shared__ __align__(16) short Bs[2][NTILE * LDSB];    // 2 x 10 KB, swizzled chunks
    __shared__ int toks[MTILE];

    const int tid = threadIdx.x;
    for (int i = tid; i < MTILE; i += 512) toks[i] = slot_t[slot_base + i];

    const int lane = tid & 63, wave = tid >> 6;       // wave 0..7
    const int mbase = (wave & 1) * 64, nbase = (wave >> 1) * 32;
    const int lc = lane & 15, q = lane >> 4;
    const int xq8 = (q ^ ((lc >> 1) & 3)) << 3;       // B frag chunk (inverse swizzle), shorts

    // A staging: wave w covers rows 16w..16w+15; lane: row w*16+(lane>>2), chunk (lane&3)*16B
    const int srow = wave * 16 + (lane >> 2);
    const int c8   = (lane & 3) * 8;

    __syncthreads();                                  // toks ready
    const short* gA = xb + (size_t)toks[srow] * DDIM + c8;
    const int lofs = wave * 512;                      // wave-uniform LDS base (shorts)

    // B staging: wave w covers k rows 4w..4w+3, lane cn covers n-pair 2cn; short4 (8B) LDS writes.
    // logical chunk = w>>1 (k octet), half = w&1; physical chunk ^= (n>>1)&3 == cn&3.
    const int cn = lane;
    const float* gW = Wf + (size_t)(4 * wave) * HDIM + n0 + 2 * cn;
    const int bws = ((((wave >> 1) ^ (cn & 3)) << 3) + (wave & 1) * 4);
    const int bofs0 = (2 * cn) * LDSB + bws, bofs1 = (2 * cn + 1) * LDSB + bws;

    floatx4 acc[4][2];
    #pragma unroll
    for (int m = 0; m < 4; m++)
        #pragma unroll
        for (int n = 0; n < 2; n++) acc[m][n] = (floatx4)0.f;

    const int NT = DDIM / KTILE;                      // 32
    float2 f[4];
    // prologue: stage t=0 into buf0, preload B regs for t=1
    #pragma unroll
    for (int j = 0; j < 4; j++) f[j] = *(const float2*)(gW + (size_t)j * HDIM);
    gld16(gA, &As[0][lofs]);
    __builtin_amdgcn_sched_barrier(0);                // pin: gld16 issued before the floads below
    {
        short4v s0, s1;
        #pragma unroll
        for (int j = 0; j < 4; j++) { s0[j] = f2b(f[j].x); s1[j] = f2b(f[j].y); }
        *(short4v*)&Bs[0][bofs0] = s0;
        *(short4v*)&Bs[0][bofs1] = s1;
    }
    #pragma unroll
    for (int j = 0; j < 4; j++) f[j] = *(const float2*)(gW + (size_t)(KTILE + j) * HDIM);
    bar_cnt4();                                       // t=0 ready (gld16 drained); f(t=1) in flight

    for (int t = 0; t < NT; t++) {
        const int cur = t & 1;
        if (t + 1 < NT) {                             // stage t+1 into other buffer (async)
            gld16(gA + (t + 1) * KTILE, &As[cur ^ 1][lofs]);
            __builtin_amdgcn_sched_barrier(0);        // keep gld16 oldest in the vmem queue
            short4v s0, s1;
            #pragma unroll
            for (int j = 0; j < 4; j++) { s0[j] = f2b(f[j].x); s1[j] = f2b(f[j].y); }
            *(short4v*)&Bs[cur ^ 1][bofs0] = s0;
            *(short4v*)&Bs[cur ^ 1][bofs1] = s1;
        }
        if (t + 2 < NT) {                             // refill B regs for t+2 (overlaps MFMA)
            #pragma unroll
            for (int j = 0; j < 4; j++)
                f[j] = *(const float2*)(gW + (size_t)((t + 2) * KTILE + j) * HDIM);
        }
        short8 af[4], bf[2];
        #pragma unroll
        for (int m = 0; m < 4; m++) af[m] = *(const short8*)&As[cur][(mbase + m * 16 + lc) * KTILE + q * 8];
        #pragma unroll
        for (int n = 0; n < 2; n++) bf[n] = *(const short8*)&Bs[cur][(nbase + n * 16 + lc) * LDSB + xq8];
        #pragma unroll
        for (int m = 0; m < 4; m++)
            #pragma unroll
            for (int n = 0; n < 2; n++)
                acc[m][n] = __builtin_amdgcn_mfma_f32_16x16x32_bf16(af[m], bf[n], acc[m][n], 0, 0, 0);
        if (t + 1 < NT) {
            if (t + 2 < NT) bar_cnt4();               // floads for t+2 stay in flight
            else            bar_cnt0();               // no younger loads -> full drain
        }
    }

    #pragma unroll
    for (int n = 0; n < 2; n++) {
        const int col = n0 + nbase + n * 16 + lc;
        const float bb = Bv[col];
        #pragma unroll
        for (int m = 0; m < 4; m++) {
            const int rbase = slot_base + mbase + m * 16 + q * 4;
            #pragma unroll
            for (int r = 0; r < 4; r++) {
                float v = acc[m][n][r] + bb;
                hh[(size_t)(rbase + r) * HDIM + col] = f2b(gelu_exact(v));
            }
        }
    }
}

// ---------------- GEMM2: eo[slot][d] = hh[slot] @ W2 + b2 (bf16, unweighted), same structure ----------------
__global__ __launch_bounds__(512) void gemm2_kernel(
    const short* __restrict__ hh,
    const float* __restrict__ w2, const float* __restrict__ b2,
    const float* __restrict__ ws2, const float* __restrict__ bs2,
    const int* __restrict__ tmap_e, const int* __restrict__ tmap_b,
    const int* __restrict__ ntl,
    short* __restrict__ eo)
{
    const int L = blockIdx.x;                         // 1024 = 8 xcd x 16 y x 8 x
    const int xcd = L & 7, sl = L >> 3;
    const int ty = xcd * 16 + sl / 8, tx = sl & 7;
    if (ty >= ntl[NEXP + 1]) return;
    const int e = tmap_e[ty];
    const int slot_base = tmap_b[ty];
    const int n0 = tx * NTILE;
    const float* __restrict__ Wf = (e < NEXP) ? (w2 + (size_t)e * HDIM * DDIM) : ws2;  // [HDIM][DDIM] fp32
    const float* __restrict__ Bv = (e < NEXP) ? (b2 + (size_t)e * DDIM) : bs2;

    __shared__ __align__(16) short As[2][MTILE * KTILE];
    __shared__ __align__(16) short Bs[2][NTILE * LDSB];

    const int tid = threadIdx.x;
    const int lane = tid & 63, wave = tid >> 6;
    const int mbase = (wave & 1) * 64, nbase = (wave >> 1) * 32;
    const int lc = lane & 15, q = lane >> 4;
    const int xq8 = (q ^ ((lc >> 1) & 3)) << 3;

    const int srow = wave * 16 + (lane >> 2);
    const int c8   = (lane & 3) * 8;

    const short* gA = hh + (size_t)(slot_base + srow) * HDIM + c8;   // slot rows contiguous
    const int lofs = wave * 512;

    const int cn = lane;
    const float* gW = Wf + (size_t)(4 * wave) * DDIM + n0 + 2 * cn;
    const int bws = ((((wave >> 1) ^ (cn & 3)) << 3) + (wave & 1) * 4);
    const int bofs0 = (2 * cn) * LDSB + bws, bofs1 = (2 * cn + 1) * LDSB + bws;

    floatx4 acc[4][2];
    #pragma unroll
    for (int m = 0; m < 4; m++)
        #pragma unroll
        for (int n = 0; n < 2; n++) acc[m][n] = (floatx4)0.f;

    const int NT = HDIM / KTILE;                      // 24
    float2 f[4];
    #pragma unroll
    for (int j = 0; j < 4; j++) f[j] = *(const float2*)(gW + (size_t)j * DDIM);
    gld16(gA, &As[0][lofs]);
    __builtin_amdgcn_sched_barrier(0);
    {
        short4v s0, s1;
        #pragma unroll
        for (int j = 0; j < 4; j++) { s0[j] = f2b(f[j].x); s1[j] = f2b(f[j].y); }
        *(short4v*)&Bs[0][bofs0] = s0;
        *(short4v*)&Bs[0][bofs1] = s1;
    }
    #pragma unroll
    for (int j = 0; j < 4; j++) f[j] = *(const float2*)(gW + (size_t)(KTILE + j) * DDIM);
    bar_cnt4();

    for (int t = 0; t < NT; t++) {
        const int cur = t & 1;
        if (t + 1 < NT) {
            gld16(gA + (t + 1) * KTILE, &As[cur ^ 1][lofs]);
            __builtin_amdgcn_sched_barrier(0);
            short4v s0, s1;
            #pragma unroll
            for (int j = 0; j < 4; j++) { s0[j] = f2b(f[j].x); s1[j] = f2b(f[j].y); }
            *(short4v*)&Bs[cur ^ 1][bofs0] = s0;
            *(short4v*)&Bs[cur ^ 1][bofs1] = s1;
        }
        if (t + 2 < NT) {
            #pragma unroll
            for (int j = 0; j < 4; j++)
                f[j] = *(const float2*)(gW + (size_t)((t + 2) * KTILE + j) * DDIM);
        }
        short8 af[4], bf[2];
        #pragma unroll
        for (int m = 0; m < 4; m++) af[m] = *(const short8*)&As[cur][(mbase + m * 16 + lc) * KTILE + q * 8];
        #pragma unroll
        for (int n = 0; n < 2; n++) bf[n] = *(const short8*)&Bs[cur][(nbase + n * 16 + lc) * LDSB + xq8];
        #pragma unroll
        for (int m = 0; m < 4; m++)
            #pragma unroll
            for (int n = 0; n < 2; n++)
                acc[m][n] = __builtin_amdgcn_mfma_f32_16x16x32_bf16(af[m], bf[n], acc[m][n], 0, 0, 0);
        if (t + 1 < NT) {
            if (t + 2 < NT) bar_cnt4();
            else            bar_cnt0();
        }
    }

    #pragma unroll
    for (int n = 0; n < 2; n++) {
        const int col = n0 + nbase + n * 16 + lc;
        const float bb = Bv[col];
        #pragma unroll
        for (int m = 0; m < 4; m++) {
            const int rbase = slot_base + mbase + m * 16 + q * 4;
            #pragma unroll
            for (int r = 0; r < 4; r++)
                eo[(size_t)(rbase + r) * DDIM + col] = f2b(acc[m][n][r] + bb);
        }
    }
}

// ---------------- combine: out[t] = eo[shared] + sum_k tw_k * eo[slot_k] ----------------
__global__ __launch_bounds__(256) void combine_kernel(
    const short* __restrict__ eo, const float* __restrict__ top_w,
    const int* __restrict__ slot_of, float* __restrict__ out)
{
    const int t = blockIdx.x;
    const int c = threadIdx.x * 4;
    const int s0 = slot_of[t * 4 + 0], s1 = slot_of[t * 4 + 1];
    const int s2 = slot_of[t * 4 + 2], s3 = slot_of[t * 4 + 3];
    const float w0 = top_w[t * 3 + 0], w1 = top_w[t * 3 + 1], w2 = top_w[t * 3 + 2];
    short4v a = *(const short4v*)(eo + (size_t)s0 * DDIM + c);
    short4v b = *(const short4v*)(eo + (size_t)s1 * DDIM + c);
    short4v d = *(const short4v*)(eo + (size_t)s2 * DDIM + c);
    short4v s = *(const short4v*)(eo + (size_t)s3 * DDIM + c);
    float4 o;
    o.x = b2f(s.x) + w0 * b2f(a.x) + w1 * b2f(b.x) + w2 * b2f(d.x);
    o.y = b2f(s.y) + w0 * b2f(a.y) + w1 * b2f(b.y) + w2 * b2f(d.y);
    o.z = b2f(s.z) + w0 * b2f(a.z) + w1 * b2f(b.z) + w2 * b2f(d.z);
    o.w = b2f(s.w) + w0 * b2f(a.w) + w1 * b2f(b.w) + w2 * b2f(d.w);
    *(float4*)(out + (size_t)t * DDIM + c) = o;
}

extern "C" void kernel_launch(void* const* d_in, const int* in_sizes, int n_in,
                              void* d_out, int out_size, void* d_ws, size_t ws_size,
                              hipStream_t stream)
{
    const float* x   = (const float*)d_in[0];
    const float* gw  = (const float*)d_in[1];
    const float* gb  = (const float*)d_in[2];
    const float* w1  = (const float*)d_in[3];
    const float* b1  = (const float*)d_in[4];
    const float* w2  = (const float*)d_in[5];
    const float* b2  = (const float*)d_in[6];
    const float* ws1 = (const float*)d_in[7];
    const float* bs1 = (const float*)d_in[8];
    const float* ws2 = (const float*)d_in[9];
    const float* bs2 = (const float*)d_in[10];
    float* out = (float*)d_out;

    char* p = (char*)d_ws;
    auto alloc = [&](size_t bytes) -> char* {
        char* r = p; p += (bytes + 255) & ~(size_t)255; return r;
    };
    int*   top_idx  = (int*)  alloc((size_t)T_TOK * 3 * 4);
    float* top_w    = (float*)alloc((size_t)T_TOK * 3 * 4);
    float* Pf       = (float*)alloc(NEXP * 4);
    int*   ntl      = (int*)  alloc((NEXP + 2) * 4);
    int*   slot_t   = (int*)  alloc((size_t)MAX_SLOTS * 4);
    int*   slot_of  = (int*)  alloc((size_t)T_TOK * 4 * 4);
    int*   tmap_e   = (int*)  alloc((size_t)MAXTILES * 4);
    int*   tmap_b   = (int*)  alloc((size_t)MAXTILES * 4);
    float* gwT      = (float*)alloc((size_t)24 * DDIM * 4);    // 24 rows: expert 23 = zero pad
    short* xb       = (short*)alloc((size_t)T_TOK * DDIM * 2);
    short* hh       = (short*)alloc((size_t)MAX_SLOTS * HDIM * 2);
    short* eo       = (short*)alloc((size_t)MAX_SLOTS * DDIM * 2);

    prep_kernel<<<XCVT_BLOCKS + DDIM / 32, 256, 0, stream>>>(x, xb, gw, gwT, Pf);
    gate_kernel<<<GATE_BLOCKS, 256, 0, stream>>>(x, gwT, gb, Pf, top_idx, top_w);
    route_kernel<<<1, 1024, 0, stream>>>(top_idx, Pf, ntl, slot_t, slot_of,
                                         tmap_e, tmap_b, out + (size_t)T_TOK * DDIM);
    gemm1_kernel<<<8 * 16 * 6, 512, 0, stream>>>(
        xb, w1, b1, ws1, bs1, tmap_e, tmap_b, ntl, slot_t, hh);
    gemm2_kernel<<<8 * 16 * 8, 512, 0, stream>>>(
        hh, w2, b2, ws2, bs2, tmap_e, tmap_b, ntl, eo);
    combine_kernel<<<T_TOK, 256, 0, stream>>>(eo, top_w, slot_of, out);
}